// Round 1
// 689.287 us; speedup vs baseline: 1.1958x; 1.1958x over previous
//
#include <hip/hip_runtime.h>

#define BB 16
#define NN 256
#define DD 64
#define EE 64
#define HH 8

__device__ __forceinline__ void fma4(float* acc, float x, float4 w) {
    acc[0] += x * w.x; acc[1] += x * w.y; acc[2] += x * w.z; acc[3] += x * w.w;
}

// ---------------------------------------------------------------------------
// Kernel 1: QKV projection.
//   Qt/Kt written TRANSPOSED [b,h,d,n] (feeds qk_kernel's conflict-free LDS
//   staging); V written [b,h,n,d] as before.
//   grid 1536 (mtx x b x n-tile-of-8), 256 threads. One matrix per block ->
//   6 blocks/CU instead of 2.
// ---------------------------------------------------------------------------
__global__ __launch_bounds__(256) void qkv_kernel(
    const float* __restrict__ query,
    const float* __restrict__ Wq, const float* __restrict__ bq,
    const float* __restrict__ Wk, const float* __restrict__ bk,
    const float* __restrict__ Wv, const float* __restrict__ bv,
    float* __restrict__ Qt, float* __restrict__ Kt, float* __restrict__ V)
{
    __shared__ __align__(16) float q_l[8][64];
    const int mtx = blockIdx.x >> 9;          // 0:Q 1:K 2:V
    const int rem = blockIdx.x & 511;
    const int b   = rem >> 5;
    const int n0  = (rem & 31) << 3;
    const int tid = threadIdx.x;

    if (tid < 128)
        ((float4*)&q_l[0][0])[tid] =
            ((const float4*)(query + (size_t)(b * NN + n0) * DD))[tid];

    const int w    = tid >> 6;                // wave -> rows 2w, 2w+1
    const int lane = tid & 63;
    const int r0   = w * 2;
    const float* W  = (mtx == 0) ? Wq : (mtx == 1) ? Wk : Wv;
    const float* bs = (mtx == 0) ? bq : (mtx == 1) ? bk : bv;

    // thread owns cols {j*256 + 4*lane .. +3} for j in {0,1}
    const int c0 = lane << 2;
    float acc[2][2][4];
    {
        const float4 b0 = *(const float4*)(bs + c0);
        const float4 b1 = *(const float4*)(bs + 256 + c0);
        acc[0][0][0]=b0.x; acc[0][0][1]=b0.y; acc[0][0][2]=b0.z; acc[0][0][3]=b0.w;
        acc[0][1][0]=b1.x; acc[0][1][1]=b1.y; acc[0][1][2]=b1.z; acc[0][1][3]=b1.w;
        acc[1][0][0]=b0.x; acc[1][0][1]=b0.y; acc[1][0][2]=b0.z; acc[1][0][3]=b0.w;
        acc[1][1][0]=b1.x; acc[1][1][1]=b1.y; acc[1][1][2]=b1.z; acc[1][1][3]=b1.w;
    }
    __syncthreads();

    #pragma unroll 2
    for (int d4 = 0; d4 < 16; ++d4) {
        const float4 qa = ((const float4*)&q_l[r0][0])[d4];
        const float4 qb = ((const float4*)&q_l[r0 + 1][0])[d4];
        const float qav[4] = {qa.x, qa.y, qa.z, qa.w};
        const float qbv[4] = {qb.x, qb.y, qb.z, qb.w};
        #pragma unroll
        for (int k = 0; k < 4; ++k) {
            const float4 w0 = *(const float4*)(W + (size_t)(d4 * 4 + k) * 512 + c0);
            const float4 w1 = *(const float4*)(W + (size_t)(d4 * 4 + k) * 512 + 256 + c0);
            fma4(acc[0][0], qav[k], w0); fma4(acc[0][1], qav[k], w1);
            fma4(acc[1][0], qbv[k], w0); fma4(acc[1][1], qbv[k], w1);
        }
    }

    const int hq = lane >> 4;                 // h within j-half
    const int d0 = (lane & 15) << 2;
    if (mtx == 2) {
        #pragma unroll
        for (int r = 0; r < 2; ++r)
            #pragma unroll
            for (int j = 0; j < 2; ++j) {
                const int h = j * 4 + hq;
                *(float4*)(V + (size_t)((b * HH + h) * NN + n0 + r0 + r) * DD + d0) =
                    make_float4(acc[r][j][0], acc[r][j][1], acc[r][j][2], acc[r][j][3]);
            }
    } else {
        float* T = (mtx == 0) ? Qt : Kt;
        #pragma unroll
        for (int r = 0; r < 2; ++r)
            #pragma unroll
            for (int j = 0; j < 2; ++j) {
                const int h = j * 4 + hq;
                #pragma unroll
                for (int k = 0; k < 4; ++k)
                    T[(size_t)((b * HH + h) * DD + d0 + k) * NN + n0 + r0 + r] =
                        acc[r][j][k];
            }
    }
}

// ---------------------------------------------------------------------------
// Kernel 2: qk = (Q @ K^T) / 8, written to scores[b,h,n,m].
//   Operands are pre-transposed [b,h,d,*] so LDS staging is linear
//   (conflict-free) and all compute reads are broadcast/consecutive b128.
//   grid 2048 (bh x 4x4 tiles of 64x64), 256 threads, 32 KB LDS.
// ---------------------------------------------------------------------------
__global__ __launch_bounds__(256) void qk_kernel(
    const float* __restrict__ Qt, const float* __restrict__ Kt,
    float* __restrict__ scores)
{
    __shared__ __align__(16) float qt_l[64][64];
    __shared__ __align__(16) float kt_l[64][64];
    const int mt  = blockIdx.x & 3;
    const int nt  = (blockIdx.x >> 2) & 3;
    const int bh  = blockIdx.x >> 4;
    const int n0  = nt << 6, m0 = mt << 6;
    const int tid = threadIdx.x;

    {   // stage 64 d-rows x 64 cols each, fully coalesced, linear LDS
        const int dr = tid >> 4;
        const int c4 = (tid & 15) << 2;
        const float* qsrc = Qt + (size_t)bh * 64 * 256 + n0;
        const float* ksrc = Kt + (size_t)bh * 64 * 256 + m0;
        #pragma unroll
        for (int it = 0; it < 4; ++it) {
            const int d = it * 16 + dr;
            *(float4*)&qt_l[d][c4] = *(const float4*)(qsrc + d * 256 + c4);
            *(float4*)&kt_l[d][c4] = *(const float4*)(ksrc + d * 256 + c4);
        }
    }
    __syncthreads();

    const int tx = tid & 15, ty = tid >> 4;   // 16x16 threads, 4x4 outputs each
    float acc[4][4] = {};
    #pragma unroll 8
    for (int d = 0; d < 64; ++d) {
        const float4 q4 = *(const float4*)&qt_l[d][ty << 2];
        const float4 k4 = *(const float4*)&kt_l[d][tx << 2];
        const float qa[4] = {q4.x, q4.y, q4.z, q4.w};
        #pragma unroll
        for (int i = 0; i < 4; ++i)
            fma4(acc[i], qa[i], k4);
    }
    float* sp = scores + ((size_t)bh * 256 + n0 + (ty << 2)) * 256 + m0 + (tx << 2);
    #pragma unroll
    for (int i = 0; i < 4; ++i)
        *(float4*)(sp + i * 256) =
            make_float4(acc[i][0] * 0.125f, acc[i][1] * 0.125f,
                        acc[i][2] * 0.125f, acc[i][3] * 0.125f);
}

// ---------------------------------------------------------------------------
// Kernel 3: fused edges pass (pure stream now: no QK compute).
//   Reads qk from scores, adds bias IN-PLACE, writes gates + edges_out.
//   All 24 long-latency loads issued up-front for MLP.
// grid 4096, 256 threads. LDS ~12.3 KB.
// ---------------------------------------------------------------------------
__global__ __launch_bounds__(256) void edges_kernel(
    const float* __restrict__ edges,
    const float* __restrict__ Wa, const float* __restrict__ ba,
    const float* __restrict__ Wg, const float* __restrict__ bg,
    const float* __restrict__ We, const float* __restrict__ be,
    float* __restrict__ scores,     // in: qk/8 ; out: qk/8 + bias
    float* __restrict__ gates,
    float* __restrict__ edges_out)
{
    __shared__ __align__(16) float wa_l[EE * HH];   // [e][h]  2 KB
    __shared__ __align__(16) float wg_l[EE * HH];   // [e][h]  2 KB
    __shared__ float ba_l[HH], bg_l[HH];
    __shared__ __align__(16) float sc_l[4][64][HH]; // 8 KB

    const int mt   = blockIdx.x & 3;
    const int nt   = (blockIdx.x >> 2) & 63;
    const int b    = blockIdx.x >> 8;
    const int n0   = nt << 2;
    const int m0   = mt << 6;
    const int tid  = threadIdx.x;
    const int lane = tid & 63;
    const int np   = tid >> 6;
    const int mp   = lane;

    for (int i = tid; i < 512; i += 256) { wa_l[i] = Wa[i]; wg_l[i] = Wg[i]; }
    if (tid < 8) { ba_l[tid] = ba[tid]; bg_l[tid] = bg[tid]; }

    float wecol[8];
    #pragma unroll
    for (int h = 0; h < 8; ++h) wecol[h] = We[h * EE + lane];
    const float bev = be[lane];

    // issue all long-latency global loads up-front
    const size_t so = (size_t)b * HH * NN * NN + (size_t)(n0 + np) * NN + m0 + mp;
    float qk[8];
    #pragma unroll
    for (int h = 0; h < 8; ++h) qk[h] = scores[so + (size_t)h * NN * NN];

    const float4* ep = (const float4*)(edges +
                        (size_t)((b * NN + n0 + np) * NN + m0 + mp) * DD);
    float4 xr[16];
    #pragma unroll
    for (int i = 0; i < 16; ++i) xr[i] = ep[i];

    __syncthreads();

    float bias[8], gate[8];
    #pragma unroll
    for (int h = 0; h < 8; ++h) { bias[h] = ba_l[h]; gate[h] = bg_l[h]; }
    #pragma unroll
    for (int e4 = 0; e4 < 16; ++e4) {
        const float xs[4] = {xr[e4].x, xr[e4].y, xr[e4].z, xr[e4].w};
        #pragma unroll
        for (int k = 0; k < 4; ++k) {
            const int e = e4 * 4 + k;
            const float4 wa0 = *(const float4*)&wa_l[e * 8];
            const float4 wa1 = *(const float4*)&wa_l[e * 8 + 4];
            const float4 wg0 = *(const float4*)&wg_l[e * 8];
            const float4 wg1 = *(const float4*)&wg_l[e * 8 + 4];
            fma4(&bias[0], xs[k], wa0); fma4(&bias[4], xs[k], wa1);
            fma4(&gate[0], xs[k], wg0); fma4(&gate[4], xs[k], wg1);
        }
    }

    float sc[8], gg[8];
    #pragma unroll
    for (int h = 0; h < 8; ++h) {
        sc[h] = qk[h] + bias[h];
        gg[h] = 1.f / (1.f + __expf(-gate[h]));
    }
    #pragma unroll
    for (int h = 0; h < 8; ++h) {
        scores[so + (size_t)h * NN * NN] = sc[h];
        gates [so + (size_t)h * NN * NN] = gg[h];
    }
    *(float4*)&sc_l[np][mp][0] = make_float4(sc[0], sc[1], sc[2], sc[3]);
    *(float4*)&sc_l[np][mp][4] = make_float4(sc[4], sc[5], sc[6], sc[7]);
    __syncthreads();

    // ---- phase 2: edges_out[b, m, n, e] = sum_h score * We[h,e] + be
    #pragma unroll 8
    for (int pi = 0; pi < 64; ++pi) {
        const int p   = np * 64 + pi;
        const int mp2 = p >> 2, np2 = p & 3;
        const float4 sa = *(const float4*)&sc_l[np2][mp2][0];
        const float4 sb = *(const float4*)&sc_l[np2][mp2][4];
        const float v = bev
            + sa.x * wecol[0] + sa.y * wecol[1] + sa.z * wecol[2] + sa.w * wecol[3]
            + sb.x * wecol[4] + sb.y * wecol[5] + sb.z * wecol[6] + sb.w * wecol[7];
        edges_out[(size_t)((b * NN + m0 + mp2) * NN + n0 + np2) * DD + lane] = v;
    }
}

// ---------------------------------------------------------------------------
// Kernel 4: Vg[b,h,n,d] = sum_m gates[b,h,n,m] * V[b,h,m,d]   (unchanged
// structure; m-loop unrolled for load batching)
// ---------------------------------------------------------------------------
__global__ __launch_bounds__(256) void vg_kernel(
    const float* __restrict__ gates, const float* __restrict__ V,
    float* __restrict__ Vg)
{
    __shared__ __align__(16) float g_l[16][256];
    const int bh  = blockIdx.x >> 4;
    const int n0  = (blockIdx.x & 15) << 4;
    const int tid = threadIdx.x;

    const float4* gsrc = (const float4*)(gates + (size_t)bh * NN * NN + (size_t)n0 * NN);
    #pragma unroll
    for (int i = 0; i < 4; ++i)
        ((float4*)&g_l[0][0])[tid + i * 256] = gsrc[tid + i * 256];
    __syncthreads();

    const int wv   = tid >> 6;
    const int msub = (tid >> 4) & 3;
    const int dq   = tid & 15;
    float acc[4][4] = {};
    const float* vb = V + (size_t)bh * NN * DD + dq * 4;
    #pragma unroll 4
    for (int mq = 0; mq < 64; ++mq) {
        const int m = mq * 4 + msub;
        const float4 v4 = *(const float4*)(vb + m * DD);
        #pragma unroll
        for (int i = 0; i < 4; ++i) {
            const float a = g_l[wv * 4 + i][m];
            acc[i][0] += a * v4.x; acc[i][1] += a * v4.y;
            acc[i][2] += a * v4.z; acc[i][3] += a * v4.w;
        }
    }
    #pragma unroll
    for (int i = 0; i < 4; ++i) {
        #pragma unroll
        for (int c = 0; c < 4; ++c) {
            acc[i][c] += __shfl_xor(acc[i][c], 16, 64);
            acc[i][c] += __shfl_xor(acc[i][c], 32, 64);
        }
        if (msub == 0)
            *(float4*)(Vg + (size_t)(bh * NN + n0 + wv * 4 + i) * DD + dq * 4) =
                make_float4(acc[i][0], acc[i][1], acc[i][2], acc[i][3]);
    }
}

// ---------------------------------------------------------------------------
// Kernel 5: softmax(scores) @ Vg, then @ Wo + bo -> attention_output.
// grid 512, 512 threads (wave = n-row). NO per-h barrier: rows are
// wave-private; the old lockstep serialized 8 waves at 2 blocks/CU.
// ---------------------------------------------------------------------------
__global__ __launch_bounds__(512) void out_kernel(
    const float* __restrict__ scores, const float* __restrict__ Vg,
    const float* __restrict__ Wo, const float* __restrict__ bo,
    float* __restrict__ att_out)
{
    __shared__ __align__(16) float att_l[8][256];
    __shared__ __align__(16) float o_l[8][512];
    const int b    = blockIdx.x >> 5;
    const int n0   = (blockIdx.x & 31) << 3;
    const int tid  = threadIdx.x;
    const int np   = tid >> 6;       // wave = row
    const int lane = tid & 63;
    const int msub = (lane >> 4) & 3;
    const int dq   = lane & 15;

    for (int h = 0; h < 8; ++h) {
        const float* sp = scores + (size_t)((b * HH + h) * NN + n0 + np) * NN;
        const float4 s4 = ((const float4*)sp)[lane];
        float mx = fmaxf(fmaxf(s4.x, s4.y), fmaxf(s4.z, s4.w));
        #pragma unroll
        for (int off = 32; off; off >>= 1) mx = fmaxf(mx, __shfl_xor(mx, off, 64));
        const float e0 = __expf(s4.x - mx), e1 = __expf(s4.y - mx),
                    e2 = __expf(s4.z - mx), e3 = __expf(s4.w - mx);
        float sm = e0 + e1 + e2 + e3;
        #pragma unroll
        for (int off = 32; off; off >>= 1) sm += __shfl_xor(sm, off, 64);
        const float inv = 1.f / sm;
        ((float4*)&att_l[np][0])[lane] = make_float4(e0 * inv, e1 * inv, e2 * inv, e3 * inv);
        // att_l row is wave-private: no barrier needed

        float a0 = 0.f, a1 = 0.f, a2 = 0.f, a3 = 0.f;
        const float* vb = Vg + (size_t)((b * HH + h) * NN) * DD + dq * 4;
        #pragma unroll 4
        for (int mq = 0; mq < 64; ++mq) {
            const int m = mq * 4 + msub;
            const float a = att_l[np][m];
            const float4 v4 = *(const float4*)(vb + m * DD);
            a0 += a * v4.x; a1 += a * v4.y; a2 += a * v4.z; a3 += a * v4.w;
        }
        a0 += __shfl_xor(a0, 16, 64); a0 += __shfl_xor(a0, 32, 64);
        a1 += __shfl_xor(a1, 16, 64); a1 += __shfl_xor(a1, 32, 64);
        a2 += __shfl_xor(a2, 16, 64); a2 += __shfl_xor(a2, 32, 64);
        a3 += __shfl_xor(a3, 16, 64); a3 += __shfl_xor(a3, 32, 64);
        if (msub == 0)
            *(float4*)&o_l[np][h * 64 + dq * 4] = make_float4(a0, a1, a2, a3);
    }

    // projection: wave np reads its own o_l row (wave-private)
    float acc = bo[lane];
    const float*  wp   = Wo + lane;
    const float4* orow = (const float4*)&o_l[np][0];
    #pragma unroll 4
    for (int k4 = 0; k4 < 128; ++k4) {
        const float4 o4 = orow[k4];
        acc += o4.x * wp[(k4 * 4 + 0) * 64] + o4.y * wp[(k4 * 4 + 1) * 64]
             + o4.z * wp[(k4 * 4 + 2) * 64] + o4.w * wp[(k4 * 4 + 3) * 64];
    }
    att_out[(size_t)(b * NN + n0 + np) * DD + lane] = acc;
}

extern "C" void kernel_launch(void* const* d_in, const int* in_sizes, int n_in,
                              void* d_out, int out_size, void* d_ws, size_t ws_size,
                              hipStream_t stream)
{
    const float* query = (const float*)d_in[0];
    const float* edges = (const float*)d_in[1];
    const float* Wq = (const float*)d_in[2];  const float* bq = (const float*)d_in[3];
    const float* Wk = (const float*)d_in[4];  const float* bk = (const float*)d_in[5];
    const float* Wv = (const float*)d_in[6];  const float* bv = (const float*)d_in[7];
    const float* Wa = (const float*)d_in[8];  const float* ba = (const float*)d_in[9];
    const float* Wg = (const float*)d_in[10]; const float* bg = (const float*)d_in[11];
    const float* Wo = (const float*)d_in[12]; const float* bo = (const float*)d_in[13];
    const float* We = (const float*)d_in[14]; const float* be = (const float*)d_in[15];

    float* att_out   = (float*)d_out;
    float* edges_out = (float*)d_out + 262144;  // B*N*D

    float* ws     = (float*)d_ws;
    float* Qt     = ws;                 // [b,h,d,n]  2,097,152 floats
    float* Kt     = ws + 2097152;       // [b,h,d,m]
    float* V      = ws + 4194304;       // [b,h,m,d]
    float* Vg     = ws + 6291456;
    float* gates  = ws + 8388608;       // 8,388,608 floats
    float* scores = ws + 16777216;      // 8,388,608 floats (qk, then in-place +bias)

    hipLaunchKernelGGL(qkv_kernel, dim3(1536), dim3(256), 0, stream,
                       query, Wq, bq, Wk, bk, Wv, bv, Qt, Kt, V);
    hipLaunchKernelGGL(qk_kernel, dim3(2048), dim3(256), 0, stream,
                       Qt, Kt, scores);
    hipLaunchKernelGGL(edges_kernel, dim3(4096), dim3(256), 0, stream,
                       edges, Wa, ba, Wg, bg, We, be, scores, gates, edges_out);
    hipLaunchKernelGGL(vg_kernel, dim3(2048), dim3(256), 0, stream,
                       gates, V, Vg);
    hipLaunchKernelGGL(out_kernel, dim3(512), dim3(512), 0, stream,
                       scores, Vg, Wo, bo, att_out);
}

// Round 2
// 601.601 us; speedup vs baseline: 1.3701x; 1.1458x over previous
//
#include <hip/hip_runtime.h>

#define BB 16
#define NN 256
#define DD 64
#define EE 64
#define HH 8

typedef __attribute__((ext_vector_type(4))) float f32x4;
typedef __attribute__((ext_vector_type(8))) short short8;

__device__ __forceinline__ void fma4(float* acc, float x, float4 w) {
    acc[0] += x * w.x; acc[1] += x * w.y; acc[2] += x * w.z; acc[3] += x * w.w;
}

// fp32 -> bf16 round-to-nearest-even
__device__ __forceinline__ unsigned short f2bf(float f) {
    union { float f; unsigned u; } v; v.f = f;
    unsigned r = v.u + 0x7FFFu + ((v.u >> 16) & 1u);
    return (unsigned short)(r >> 16);
}

// ---------------------------------------------------------------------------
// Kernel 1: QKV projection (fp32 compute), bf16 outputs:
//   Qb [b,h,n,d] (pre-scaled by 0.125), Kb [b,h,n,d], Vtb [b,h,d,n] (transposed).
// grid 1536 (mtx x b x n-tile-of-8), 256 threads.
// ---------------------------------------------------------------------------
__global__ __launch_bounds__(256) void qkv_kernel(
    const float* __restrict__ query,
    const float* __restrict__ Wq, const float* __restrict__ bq,
    const float* __restrict__ Wk, const float* __restrict__ bk,
    const float* __restrict__ Wv, const float* __restrict__ bv,
    unsigned short* __restrict__ Qb, unsigned short* __restrict__ Kb,
    unsigned short* __restrict__ Vtb)
{
    __shared__ __align__(16) float q_l[8][64];
    const int mtx = blockIdx.x >> 9;          // 0:Q 1:K 2:V
    const int rem = blockIdx.x & 511;
    const int b   = rem >> 5;
    const int n0  = (rem & 31) << 3;
    const int tid = threadIdx.x;

    if (tid < 128)
        ((float4*)&q_l[0][0])[tid] =
            ((const float4*)(query + (size_t)(b * NN + n0) * DD))[tid];

    const int w    = tid >> 6;                // wave -> rows 2w, 2w+1
    const int lane = tid & 63;
    const int r0   = w * 2;
    const float* W  = (mtx == 0) ? Wq : (mtx == 1) ? Wk : Wv;
    const float* bs = (mtx == 0) ? bq : (mtx == 1) ? bk : bv;

    const int c0 = lane << 2;
    float acc[2][2][4];
    {
        const float4 b0 = *(const float4*)(bs + c0);
        const float4 b1 = *(const float4*)(bs + 256 + c0);
        acc[0][0][0]=b0.x; acc[0][0][1]=b0.y; acc[0][0][2]=b0.z; acc[0][0][3]=b0.w;
        acc[0][1][0]=b1.x; acc[0][1][1]=b1.y; acc[0][1][2]=b1.z; acc[0][1][3]=b1.w;
        acc[1][0][0]=b0.x; acc[1][0][1]=b0.y; acc[1][0][2]=b0.z; acc[1][0][3]=b0.w;
        acc[1][1][0]=b1.x; acc[1][1][1]=b1.y; acc[1][1][2]=b1.z; acc[1][1][3]=b1.w;
    }
    __syncthreads();

    #pragma unroll 2
    for (int d4 = 0; d4 < 16; ++d4) {
        const float4 qa = ((const float4*)&q_l[r0][0])[d4];
        const float4 qb = ((const float4*)&q_l[r0 + 1][0])[d4];
        const float qav[4] = {qa.x, qa.y, qa.z, qa.w};
        const float qbv[4] = {qb.x, qb.y, qb.z, qb.w};
        #pragma unroll
        for (int k = 0; k < 4; ++k) {
            const float4 w0 = *(const float4*)(W + (size_t)(d4 * 4 + k) * 512 + c0);
            const float4 w1 = *(const float4*)(W + (size_t)(d4 * 4 + k) * 512 + 256 + c0);
            fma4(acc[0][0], qav[k], w0); fma4(acc[0][1], qav[k], w1);
            fma4(acc[1][0], qbv[k], w0); fma4(acc[1][1], qbv[k], w1);
        }
    }

    const int hq = lane >> 4;                 // h within j-half
    const int d0 = (lane & 15) << 2;
    if (mtx < 2) {
        unsigned short* T = (mtx == 0) ? Qb : Kb;
        const float scale = (mtx == 0) ? 0.125f : 1.0f;
        #pragma unroll
        for (int r = 0; r < 2; ++r)
            #pragma unroll
            for (int j = 0; j < 2; ++j) {
                const int h = j * 4 + hq;
                const unsigned int lo = (unsigned)f2bf(acc[r][j][0] * scale)
                                      | ((unsigned)f2bf(acc[r][j][1] * scale) << 16);
                const unsigned int hi = (unsigned)f2bf(acc[r][j][2] * scale)
                                      | ((unsigned)f2bf(acc[r][j][3] * scale) << 16);
                uint2* p = (uint2*)(T + ((size_t)(b * HH + h) * NN + n0 + r0 + r) * DD + d0);
                *p = make_uint2(lo, hi);
            }
    } else {
        #pragma unroll
        for (int r = 0; r < 2; ++r)
            #pragma unroll
            for (int j = 0; j < 2; ++j) {
                const int h = j * 4 + hq;
                #pragma unroll
                for (int k = 0; k < 4; ++k)
                    Vtb[((size_t)(b * HH + h) * DD + d0 + k) * NN + n0 + r0 + r] =
                        f2bf(acc[r][j][k]);
            }
    }
}

// ---------------------------------------------------------------------------
// Kernel 2: scores = (Q @ K^T)/8 via bf16 MFMA (scale folded into Qb).
//   Lane l: A row n0+(l&15), B row m+(l&15); both read 8 contiguous d (16B).
// grid 1024 (bh x 4 n-tiles-of-64 x 2 m-halves-of-128), 256 thr, no LDS.
// ---------------------------------------------------------------------------
__global__ __launch_bounds__(256) void qk_kernel(
    const unsigned short* __restrict__ Qb, const unsigned short* __restrict__ Kb,
    float* __restrict__ scores)
{
    const int bh = blockIdx.x >> 3;
    const int nt = (blockIdx.x >> 1) & 3;
    const int mh = blockIdx.x & 1;
    const int tid = threadIdx.x;
    const int w = tid >> 6, l = tid & 63;
    const int lr = l & 15, lg = l >> 4;
    const int n0 = nt * 64 + w * 16;

    const unsigned short* qp = Qb + ((size_t)bh * NN + n0 + lr) * DD + lg * 8;
    const unsigned short* kp = Kb + ((size_t)bh * NN + mh * 128 + lr) * DD + lg * 8;

    const short8 a0 = *(const short8*)qp;
    const short8 a1 = *(const short8*)(qp + 32);

    f32x4 acc[8];
    #pragma unroll
    for (int mt = 0; mt < 8; ++mt) acc[mt] = (f32x4){0.f, 0.f, 0.f, 0.f};

    #pragma unroll
    for (int mt = 0; mt < 8; ++mt) {
        const short8 b0 = *(const short8*)(kp + (size_t)mt * 16 * DD);
        const short8 b1 = *(const short8*)(kp + (size_t)mt * 16 * DD + 32);
        acc[mt] = __builtin_amdgcn_mfma_f32_16x16x32_bf16(a0, b0, acc[mt], 0, 0, 0);
        acc[mt] = __builtin_amdgcn_mfma_f32_16x16x32_bf16(a1, b1, acc[mt], 0, 0, 0);
    }

    float* sp = scores + (size_t)bh * NN * NN;
    #pragma unroll
    for (int mt = 0; mt < 8; ++mt)
        #pragma unroll
        for (int r = 0; r < 4; ++r)
            sp[(size_t)(n0 + lg * 4 + r) * NN + mh * 128 + mt * 16 + lr] = acc[mt][r];
}

// ---------------------------------------------------------------------------
// Kernel 3: fused edges pass. Reads qk/8 from scores, adds bias IN-PLACE,
// writes gates (bf16 now) + edges_out. Pure stream, loads issued up-front.
// grid 4096, 256 threads.
// ---------------------------------------------------------------------------
__global__ __launch_bounds__(256) void edges_kernel(
    const float* __restrict__ edges,
    const float* __restrict__ Wa, const float* __restrict__ ba,
    const float* __restrict__ Wg, const float* __restrict__ bg,
    const float* __restrict__ We, const float* __restrict__ be,
    float* __restrict__ scores,
    unsigned short* __restrict__ gates,
    float* __restrict__ edges_out)
{
    __shared__ __align__(16) float wa_l[EE * HH];
    __shared__ __align__(16) float wg_l[EE * HH];
    __shared__ float ba_l[HH], bg_l[HH];
    __shared__ __align__(16) float sc_l[4][64][HH];

    const int mt   = blockIdx.x & 3;
    const int nt   = (blockIdx.x >> 2) & 63;
    const int b    = blockIdx.x >> 8;
    const int n0   = nt << 2;
    const int m0   = mt << 6;
    const int tid  = threadIdx.x;
    const int lane = tid & 63;
    const int np   = tid >> 6;
    const int mp   = lane;

    for (int i = tid; i < 512; i += 256) { wa_l[i] = Wa[i]; wg_l[i] = Wg[i]; }
    if (tid < 8) { ba_l[tid] = ba[tid]; bg_l[tid] = bg[tid]; }

    float wecol[8];
    #pragma unroll
    for (int h = 0; h < 8; ++h) wecol[h] = We[h * EE + lane];
    const float bev = be[lane];

    const size_t so = (size_t)b * HH * NN * NN + (size_t)(n0 + np) * NN + m0 + mp;
    float qk[8];
    #pragma unroll
    for (int h = 0; h < 8; ++h) qk[h] = scores[so + (size_t)h * NN * NN];

    const float4* ep = (const float4*)(edges +
                        (size_t)((b * NN + n0 + np) * NN + m0 + mp) * DD);
    float4 xr[16];
    #pragma unroll
    for (int i = 0; i < 16; ++i) xr[i] = ep[i];

    __syncthreads();

    float bias[8], gate[8];
    #pragma unroll
    for (int h = 0; h < 8; ++h) { bias[h] = ba_l[h]; gate[h] = bg_l[h]; }
    #pragma unroll
    for (int e4 = 0; e4 < 16; ++e4) {
        const float xs[4] = {xr[e4].x, xr[e4].y, xr[e4].z, xr[e4].w};
        #pragma unroll
        for (int k = 0; k < 4; ++k) {
            const int e = e4 * 4 + k;
            const float4 wa0 = *(const float4*)&wa_l[e * 8];
            const float4 wa1 = *(const float4*)&wa_l[e * 8 + 4];
            const float4 wg0 = *(const float4*)&wg_l[e * 8];
            const float4 wg1 = *(const float4*)&wg_l[e * 8 + 4];
            fma4(&bias[0], xs[k], wa0); fma4(&bias[4], xs[k], wa1);
            fma4(&gate[0], xs[k], wg0); fma4(&gate[4], xs[k], wg1);
        }
    }

    float sc[8];
    #pragma unroll
    for (int h = 0; h < 8; ++h) {
        sc[h] = qk[h] + bias[h];
        const float gg = 1.f / (1.f + __expf(-gate[h]));
        scores[so + (size_t)h * NN * NN] = sc[h];
        gates [so + (size_t)h * NN * NN] = f2bf(gg);
    }
    *(float4*)&sc_l[np][mp][0] = make_float4(sc[0], sc[1], sc[2], sc[3]);
    *(float4*)&sc_l[np][mp][4] = make_float4(sc[4], sc[5], sc[6], sc[7]);
    __syncthreads();

    #pragma unroll 8
    for (int pi = 0; pi < 64; ++pi) {
        const int p   = np * 64 + pi;
        const int mp2 = p >> 2, np2 = p & 3;
        const float4 sa = *(const float4*)&sc_l[np2][mp2][0];
        const float4 sb = *(const float4*)&sc_l[np2][mp2][4];
        const float v = bev
            + sa.x * wecol[0] + sa.y * wecol[1] + sa.z * wecol[2] + sa.w * wecol[3]
            + sb.x * wecol[4] + sb.y * wecol[5] + sb.z * wecol[6] + sb.w * wecol[7];
        edges_out[(size_t)((b * NN + m0 + mp2) * NN + n0 + np2) * DD + lane] = v;
    }
}

// ---------------------------------------------------------------------------
// Kernel 4: Vgt[b,h,d,n] = (V^T @ g^T) via bf16 MFMA.
//   A = Vtb rows (d), B-frag = gate rows (n); K = m = 256 (8 ksteps).
// grid 512 (bh x 4 n-quarters), 256 threads, no LDS.
// ---------------------------------------------------------------------------
__global__ __launch_bounds__(256) void vg_kernel(
    const unsigned short* __restrict__ gates, const unsigned short* __restrict__ Vtb,
    unsigned short* __restrict__ Vgt)
{
    const int bh = blockIdx.x >> 2;
    const int q  = blockIdx.x & 3;
    const int tid = threadIdx.x;
    const int w = tid >> 6, l = tid & 63;
    const int lr = l & 15, lg = l >> 4;
    const int n0 = q * 64 + w * 16;

    const unsigned short* gp = gates + ((size_t)bh * NN + n0 + lr) * NN + lg * 8;
    const unsigned short* vp = Vtb + ((size_t)bh * DD + lr) * NN + lg * 8;

    f32x4 acc[4];
    #pragma unroll
    for (int dt = 0; dt < 4; ++dt) acc[dt] = (f32x4){0.f, 0.f, 0.f, 0.f};

    #pragma unroll
    for (int ks = 0; ks < 8; ++ks) {
        const short8 bfr = *(const short8*)(gp + ks * 32);
        #pragma unroll
        for (int dt = 0; dt < 4; ++dt) {
            const short8 afr = *(const short8*)(vp + (size_t)dt * 16 * NN + ks * 32);
            acc[dt] = __builtin_amdgcn_mfma_f32_16x16x32_bf16(afr, bfr, acc[dt], 0, 0, 0);
        }
    }

    unsigned short* op = Vgt + (size_t)bh * DD * NN;
    #pragma unroll
    for (int dt = 0; dt < 4; ++dt)
        #pragma unroll
        for (int r = 0; r < 4; ++r)
            op[(size_t)(dt * 16 + lg * 4 + r) * NN + n0 + lr] = f2bf(acc[dt][r]);
}

// ---------------------------------------------------------------------------
// Kernel 5: softmax(scores) @ Vg + projection, via bf16 MFMA (out^T form).
//   Lane l owns score row n0+(l&15), m-slots (l>>4)*8+j per kstep -> probs
//   are born in B-fragment layout; row-reduce = 2 shfl_xor. A = Vgt rows.
//   Wave w handles h = {w, w+4}. out^T frags -> LDS -> fp32 projection.
// grid 256 (b x 16 n-tiles), 256 threads, LDS 32.8 KB.
// ---------------------------------------------------------------------------
__global__ __launch_bounds__(256) void out_kernel(
    const float* __restrict__ scores, const unsigned short* __restrict__ Vgt,
    const float* __restrict__ Wo, const float* __restrict__ bo,
    float* __restrict__ att_out)
{
    __shared__ __align__(16) float o_l[16][513];
    const int b  = blockIdx.x >> 4;
    const int nt = blockIdx.x & 15;
    const int n0 = nt * 16;
    const int tid = threadIdx.x;
    const int w = tid >> 6, l = tid & 63;
    const int lr = l & 15, lg = l >> 4;

    #pragma unroll
    for (int hw = 0; hw < 2; ++hw) {
        const int h = w + hw * 4;
        const float* sp = scores + ((size_t)(b * HH + h) * NN + n0 + lr) * NN + lg * 8;

        float s[64];
        #pragma unroll
        for (int ks = 0; ks < 8; ++ks) {
            const float4 x0 = *(const float4*)(sp + ks * 32);
            const float4 x1 = *(const float4*)(sp + ks * 32 + 4);
            s[ks * 8 + 0] = x0.x; s[ks * 8 + 1] = x0.y;
            s[ks * 8 + 2] = x0.z; s[ks * 8 + 3] = x0.w;
            s[ks * 8 + 4] = x1.x; s[ks * 8 + 5] = x1.y;
            s[ks * 8 + 6] = x1.z; s[ks * 8 + 7] = x1.w;
        }
        float mx = -1e30f;
        #pragma unroll
        for (int i = 0; i < 64; ++i) mx = fmaxf(mx, s[i]);
        mx = fmaxf(mx, __shfl_xor(mx, 16, 64));
        mx = fmaxf(mx, __shfl_xor(mx, 32, 64));
        float sm = 0.f;
        #pragma unroll
        for (int i = 0; i < 64; ++i) { s[i] = __expf(s[i] - mx); sm += s[i]; }
        sm += __shfl_xor(sm, 16, 64);
        sm += __shfl_xor(sm, 32, 64);
        const float inv = 1.f / sm;

        const unsigned short* vp = Vgt + ((size_t)(b * HH + h) * DD + lr) * NN + lg * 8;
        f32x4 acc[4];
        #pragma unroll
        for (int dt = 0; dt < 4; ++dt) acc[dt] = (f32x4){0.f, 0.f, 0.f, 0.f};

        #pragma unroll
        for (int ks = 0; ks < 8; ++ks) {
            union { short8 v; unsigned short u[8]; } bf;
            #pragma unroll
            for (int j = 0; j < 8; ++j) bf.u[j] = f2bf(s[ks * 8 + j] * inv);
            #pragma unroll
            for (int dt = 0; dt < 4; ++dt) {
                const short8 afr = *(const short8*)(vp + (size_t)dt * 16 * NN + ks * 32);
                acc[dt] = __builtin_amdgcn_mfma_f32_16x16x32_bf16(afr, bf.v, acc[dt], 0, 0, 0);
            }
        }
        // C: row = d' = dt*16+lg*4+r, col = n' = lr
        #pragma unroll
        for (int dt = 0; dt < 4; ++dt)
            #pragma unroll
            for (int r = 0; r < 4; ++r)
                o_l[lr][h * 64 + dt * 16 + lg * 4 + r] = acc[dt][r];
    }
    __syncthreads();

    // projection: thread (n = tid>>4, d4 = (tid&15)*4); o_l row broadcast, Wo coalesced
    const int n  = tid >> 4;
    const int d4 = (tid & 15) << 2;
    float a0 = bo[d4], a1 = bo[d4 + 1], a2 = bo[d4 + 2], a3 = bo[d4 + 3];
    const float* orow = &o_l[n][0];
    #pragma unroll 8
    for (int k = 0; k < 512; ++k) {
        const float o = orow[k];
        const float4 w4 = *(const float4*)(Wo + (size_t)k * 64 + d4);
        a0 += o * w4.x; a1 += o * w4.y; a2 += o * w4.z; a3 += o * w4.w;
    }
    *(float4*)(att_out + ((size_t)(b * NN + n0 + n)) * DD + d4) =
        make_float4(a0, a1, a2, a3);
}

extern "C" void kernel_launch(void* const* d_in, const int* in_sizes, int n_in,
                              void* d_out, int out_size, void* d_ws, size_t ws_size,
                              hipStream_t stream)
{
    const float* query = (const float*)d_in[0];
    const float* edges = (const float*)d_in[1];
    const float* Wq = (const float*)d_in[2];  const float* bq = (const float*)d_in[3];
    const float* Wk = (const float*)d_in[4];  const float* bk = (const float*)d_in[5];
    const float* Wv = (const float*)d_in[6];  const float* bv = (const float*)d_in[7];
    const float* Wa = (const float*)d_in[8];  const float* ba = (const float*)d_in[9];
    const float* Wg = (const float*)d_in[10]; const float* bg = (const float*)d_in[11];
    const float* Wo = (const float*)d_in[12]; const float* bo = (const float*)d_in[13];
    const float* We = (const float*)d_in[14]; const float* be = (const float*)d_in[15];

    float* att_out   = (float*)d_out;
    float* edges_out = (float*)d_out + 262144;  // B*N*D

    char* base = (char*)d_ws;
    float*          scores = (float*)base;                          // 33,554,432 B
    unsigned short* gates  = (unsigned short*)(base + 33554432);    // 16,777,216 B
    unsigned short* Qb     = (unsigned short*)(base + 50331648);    //  4,194,304 B
    unsigned short* Kb     = (unsigned short*)(base + 54525952);    //  4,194,304 B
    unsigned short* Vtb    = (unsigned short*)(base + 58720256);    //  4,194,304 B
    unsigned short* Vgt    = (unsigned short*)(base + 62914560);    //  4,194,304 B

    hipLaunchKernelGGL(qkv_kernel, dim3(1536), dim3(256), 0, stream,
                       query, Wq, bq, Wk, bk, Wv, bv, Qb, Kb, Vtb);
    hipLaunchKernelGGL(qk_kernel, dim3(1024), dim3(256), 0, stream,
                       Qb, Kb, scores);
    hipLaunchKernelGGL(edges_kernel, dim3(4096), dim3(256), 0, stream,
                       edges, Wa, ba, Wg, bg, We, be, scores, gates, edges_out);
    hipLaunchKernelGGL(vg_kernel, dim3(512), dim3(256), 0, stream,
                       gates, Vtb, Vgt);
    hipLaunchKernelGGL(out_kernel, dim3(256), dim3(256), 0, stream,
                       scores, Vgt, Wo, bo, att_out);
}

// Round 3
// 588.840 us; speedup vs baseline: 1.3998x; 1.0217x over previous
//
#include <hip/hip_runtime.h>

#define BB 16
#define NN 256
#define DD 64
#define EE 64
#define HH 8

typedef __attribute__((ext_vector_type(4))) float f32x4;
typedef __attribute__((ext_vector_type(8))) short short8;

__device__ __forceinline__ void fma4(float* acc, float x, float4 w) {
    acc[0] += x * w.x; acc[1] += x * w.y; acc[2] += x * w.z; acc[3] += x * w.w;
}

// fp32 -> bf16 round-to-nearest-even
__device__ __forceinline__ unsigned short f2bf(float f) {
    union { float f; unsigned u; } v; v.f = f;
    unsigned r = v.u + 0x7FFFu + ((v.u >> 16) & 1u);
    return (unsigned short)(r >> 16);
}

// ---------------------------------------------------------------------------
// Kernel 1: QKV projection (fp32 compute), bf16 outputs:
//   Qb [b,h,n,d] (pre-scaled by 0.125), Kb [b,h,n,d], Vtb [b,h,d,n] (transposed).
// grid 1536 (mtx x b x n-tile-of-8), 256 threads.
// ---------------------------------------------------------------------------
__global__ __launch_bounds__(256) void qkv_kernel(
    const float* __restrict__ query,
    const float* __restrict__ Wq, const float* __restrict__ bq,
    const float* __restrict__ Wk, const float* __restrict__ bk,
    const float* __restrict__ Wv, const float* __restrict__ bv,
    unsigned short* __restrict__ Qb, unsigned short* __restrict__ Kb,
    unsigned short* __restrict__ Vtb)
{
    __shared__ __align__(16) float q_l[8][64];
    const int mtx = blockIdx.x >> 9;          // 0:Q 1:K 2:V
    const int rem = blockIdx.x & 511;
    const int b   = rem >> 5;
    const int n0  = (rem & 31) << 3;
    const int tid = threadIdx.x;

    if (tid < 128)
        ((float4*)&q_l[0][0])[tid] =
            ((const float4*)(query + (size_t)(b * NN + n0) * DD))[tid];

    const int w    = tid >> 6;                // wave -> rows 2w, 2w+1
    const int lane = tid & 63;
    const int r0   = w * 2;
    const float* W  = (mtx == 0) ? Wq : (mtx == 1) ? Wk : Wv;
    const float* bs = (mtx == 0) ? bq : (mtx == 1) ? bk : bv;

    const int c0 = lane << 2;
    float acc[2][2][4];
    {
        const float4 b0 = *(const float4*)(bs + c0);
        const float4 b1 = *(const float4*)(bs + 256 + c0);
        acc[0][0][0]=b0.x; acc[0][0][1]=b0.y; acc[0][0][2]=b0.z; acc[0][0][3]=b0.w;
        acc[0][1][0]=b1.x; acc[0][1][1]=b1.y; acc[0][1][2]=b1.z; acc[0][1][3]=b1.w;
        acc[1][0][0]=b0.x; acc[1][0][1]=b0.y; acc[1][0][2]=b0.z; acc[1][0][3]=b0.w;
        acc[1][1][0]=b1.x; acc[1][1][1]=b1.y; acc[1][1][2]=b1.z; acc[1][1][3]=b1.w;
    }
    __syncthreads();

    #pragma unroll 2
    for (int d4 = 0; d4 < 16; ++d4) {
        const float4 qa = ((const float4*)&q_l[r0][0])[d4];
        const float4 qb = ((const float4*)&q_l[r0 + 1][0])[d4];
        const float qav[4] = {qa.x, qa.y, qa.z, qa.w};
        const float qbv[4] = {qb.x, qb.y, qb.z, qb.w};
        #pragma unroll
        for (int k = 0; k < 4; ++k) {
            const float4 w0 = *(const float4*)(W + (size_t)(d4 * 4 + k) * 512 + c0);
            const float4 w1 = *(const float4*)(W + (size_t)(d4 * 4 + k) * 512 + 256 + c0);
            fma4(acc[0][0], qav[k], w0); fma4(acc[0][1], qav[k], w1);
            fma4(acc[1][0], qbv[k], w0); fma4(acc[1][1], qbv[k], w1);
        }
    }

    const int hq = lane >> 4;                 // h within j-half
    const int d0 = (lane & 15) << 2;
    if (mtx < 2) {
        unsigned short* T = (mtx == 0) ? Qb : Kb;
        const float scale = (mtx == 0) ? 0.125f : 1.0f;
        #pragma unroll
        for (int r = 0; r < 2; ++r)
            #pragma unroll
            for (int j = 0; j < 2; ++j) {
                const int h = j * 4 + hq;
                const unsigned int lo = (unsigned)f2bf(acc[r][j][0] * scale)
                                      | ((unsigned)f2bf(acc[r][j][1] * scale) << 16);
                const unsigned int hi = (unsigned)f2bf(acc[r][j][2] * scale)
                                      | ((unsigned)f2bf(acc[r][j][3] * scale) << 16);
                uint2* p = (uint2*)(T + ((size_t)(b * HH + h) * NN + n0 + r0 + r) * DD + d0);
                *p = make_uint2(lo, hi);
            }
    } else {
        #pragma unroll
        for (int r = 0; r < 2; ++r)
            #pragma unroll
            for (int j = 0; j < 2; ++j) {
                const int h = j * 4 + hq;
                #pragma unroll
                for (int k = 0; k < 4; ++k)
                    Vtb[((size_t)(b * HH + h) * DD + d0 + k) * NN + n0 + r0 + r] =
                        f2bf(acc[r][j][k]);
            }
    }
}

// ---------------------------------------------------------------------------
// Kernel 2: scores = (Q @ K^T)/8 via bf16 MFMA (scale folded into Qb).
// grid 1024 (bh x 4 n-tiles-of-64 x 2 m-halves-of-128), 256 thr, no LDS.
// ---------------------------------------------------------------------------
__global__ __launch_bounds__(256) void qk_kernel(
    const unsigned short* __restrict__ Qb, const unsigned short* __restrict__ Kb,
    float* __restrict__ scores)
{
    const int bh = blockIdx.x >> 3;
    const int nt = (blockIdx.x >> 1) & 3;
    const int mh = blockIdx.x & 1;
    const int tid = threadIdx.x;
    const int w = tid >> 6, l = tid & 63;
    const int lr = l & 15, lg = l >> 4;
    const int n0 = nt * 64 + w * 16;

    const unsigned short* qp = Qb + ((size_t)bh * NN + n0 + lr) * DD + lg * 8;
    const unsigned short* kp = Kb + ((size_t)bh * NN + mh * 128 + lr) * DD + lg * 8;

    const short8 a0 = *(const short8*)qp;
    const short8 a1 = *(const short8*)(qp + 32);

    f32x4 acc[8];
    #pragma unroll
    for (int mt = 0; mt < 8; ++mt) acc[mt] = (f32x4){0.f, 0.f, 0.f, 0.f};

    #pragma unroll
    for (int mt = 0; mt < 8; ++mt) {
        const short8 b0 = *(const short8*)(kp + (size_t)mt * 16 * DD);
        const short8 b1 = *(const short8*)(kp + (size_t)mt * 16 * DD + 32);
        acc[mt] = __builtin_amdgcn_mfma_f32_16x16x32_bf16(a0, b0, acc[mt], 0, 0, 0);
        acc[mt] = __builtin_amdgcn_mfma_f32_16x16x32_bf16(a1, b1, acc[mt], 0, 0, 0);
    }

    float* sp = scores + (size_t)bh * NN * NN;
    #pragma unroll
    for (int mt = 0; mt < 8; ++mt)
        #pragma unroll
        for (int r = 0; r < 4; ++r)
            sp[(size_t)(n0 + lg * 4 + r) * NN + mh * 128 + mt * 16 + lr] = acc[mt][r];
}

// ---------------------------------------------------------------------------
// Kernel 3: fused edges pass, fully coalesced.
//   block = (b, n, m-half of 128). Stage edges tile [128 m][64 e] (contiguous
//   memory!) coalesced -> bf16 LDS (XOR swizzle). MLP = MFMA GEMM
//   [128,64]@[64,16] (Wa|Wg). Fixup adds qk+ba (coalesced), writes scores +
//   gates (coalesced). Phase 2 streams edges_out from LDS broadcasts.
// grid 8192, 256 threads, LDS ~27 KB -> 5 blocks/CU.
// ---------------------------------------------------------------------------
__global__ __launch_bounds__(256) void edges_kernel(
    const float* __restrict__ edges,
    const float* __restrict__ Wa, const float* __restrict__ ba,
    const float* __restrict__ Wg, const float* __restrict__ bg,
    const float* __restrict__ We, const float* __restrict__ be,
    float* __restrict__ scores,
    unsigned short* __restrict__ gates,
    float* __restrict__ edges_out)
{
    __shared__ __align__(16) unsigned short eb[128 * 64];   // 16 KB, swizzled
    __shared__ __align__(16) unsigned short wc[16 * 64];    //  2 KB, WcatT[h'][e]
    __shared__ float bgl[128][17];                          // 8.7 KB (odd stride)
    __shared__ float bal[8], bgb[8];

    const int mh  = blockIdx.x & 1;
    const int n   = (blockIdx.x >> 1) & 255;
    const int b   = blockIdx.x >> 9;
    const int m0  = mh << 7;
    const int tid = threadIdx.x;
    const int w   = tid >> 6, l = tid & 63;
    const int lr  = l & 15, lg = l >> 4;

    // preload phase-2 constants early (overlaps staging latency)
    float wecol[8];
    #pragma unroll
    for (int h = 0; h < 8; ++h) wecol[h] = We[h * EE + l];
    const float bev = be[l];

    // --- stage WcatT[h'][e] bf16 (h'<8 -> Wa, else Wg), swizzled
    #pragma unroll
    for (int j = 0; j < 4; ++j) {
        const int idx = tid * 4 + j;
        const int hp = idx >> 6, e = idx & 63;
        const float v = (hp < 8) ? Wa[e * 8 + hp] : Wg[e * 8 + (hp - 8)];
        *(unsigned short*)((char*)wc + hp * 128 + ((e * 2) ^ ((hp & 7) << 4))) = f2bf(v);
    }
    if (tid < 8) { bal[tid] = ba[tid]; bgb[tid] = bg[tid]; }

    // --- stage edges tile [128][64] fp32 -> bf16 LDS, coalesced global reads
    const float4* esrc = (const float4*)(edges + ((size_t)(b * NN + n) * NN + m0) * DD);
    #pragma unroll
    for (int it = 0; it < 8; ++it) {
        const int c = it * 256 + tid;            // float4 index: m = c>>4, e4 = c&15
        const float4 x = esrc[c];
        const int m = c >> 4, e4 = c & 15;
        const unsigned lo = (unsigned)f2bf(x.x) | ((unsigned)f2bf(x.y) << 16);
        const unsigned hi = (unsigned)f2bf(x.z) | ((unsigned)f2bf(x.w) << 16);
        *(uint2*)((char*)eb + m * 128 + ((e4 * 8) ^ ((m & 7) << 4))) = make_uint2(lo, hi);
    }
    __syncthreads();

    // --- B fragments (WcatT rows, conflict-free via swizzle)
    short8 bfrag[2];
    #pragma unroll
    for (int ks = 0; ks < 2; ++ks)
        bfrag[ks] = *(const short8*)((char*)wc + lr * 128 +
                                     ((ks * 64 + lg * 16) ^ ((lr & 7) << 4)));

    // --- MFMA MLP: wave w owns m-tiles {2w, 2w+1}
    #pragma unroll
    for (int t = 0; t < 2; ++t) {
        const int T = w * 2 + t;
        f32x4 acc = (f32x4){0.f, 0.f, 0.f, 0.f};
        #pragma unroll
        for (int ks = 0; ks < 2; ++ks) {
            const int m = T * 16 + lr;
            const short8 af = *(const short8*)((char*)eb + m * 128 +
                                 ((ks * 64 + lg * 16) ^ ((lr & 7) << 4)));
            acc = __builtin_amdgcn_mfma_f32_16x16x32_bf16(af, bfrag[ks], acc, 0, 0, 0);
        }
        // C: col (h') = lr, row (m-in-tile) = lg*4 + r
        #pragma unroll
        for (int r = 0; r < 4; ++r)
            bgl[T * 16 + lg * 4 + r][lr] = acc[r];
    }
    __syncthreads();

    // --- fixup: thread = (hh = tid>>7, m = tid&127); coalesced qk/score/gate
    {
        const int m  = tid & 127;
        const int hh = tid >> 7;
        #pragma unroll
        for (int i = 0; i < 4; ++i) {
            const int h = hh * 4 + i;
            const size_t off = ((size_t)(b * HH + h) << 16) + (n << 8) + m0 + m;
            const float sc = scores[off] + bgl[m][h] + bal[h];
            scores[off] = sc;
            bgl[m][h]   = sc;                            // slot owned by this thread
            const float gv = bgl[m][8 + h] + bgb[h];
            gates[off] = f2bf(1.f / (1.f + __expf(-gv)));
        }
    }
    __syncthreads();

    // --- phase 2: edges_out[b, m, n, e] = sum_h sc[m][h] * We[h][e] + be[e]
    #pragma unroll 4
    for (int mi = 0; mi < 32; ++mi) {
        const int m = w * 32 + mi;
        float v = bev;
        #pragma unroll
        for (int h = 0; h < 8; ++h) v += bgl[m][h] * wecol[h];   // LDS broadcast
        edges_out[((size_t)(b * NN + m0 + m) * NN + n) * DD + l] = v;
    }
}

// ---------------------------------------------------------------------------
// Kernel 4: Vgt[b,h,d,n] = (V^T @ g^T) via bf16 MFMA.
// grid 512 (bh x 4 n-quarters), 256 threads, no LDS.
// ---------------------------------------------------------------------------
__global__ __launch_bounds__(256) void vg_kernel(
    const unsigned short* __restrict__ gates, const unsigned short* __restrict__ Vtb,
    unsigned short* __restrict__ Vgt)
{
    const int bh = blockIdx.x >> 2;
    const int q  = blockIdx.x & 3;
    const int tid = threadIdx.x;
    const int w = tid >> 6, l = tid & 63;
    const int lr = l & 15, lg = l >> 4;
    const int n0 = q * 64 + w * 16;

    const unsigned short* gp = gates + ((size_t)bh * NN + n0 + lr) * NN + lg * 8;
    const unsigned short* vp = Vtb + ((size_t)bh * DD + lr) * NN + lg * 8;

    f32x4 acc[4];
    #pragma unroll
    for (int dt = 0; dt < 4; ++dt) acc[dt] = (f32x4){0.f, 0.f, 0.f, 0.f};

    #pragma unroll
    for (int ks = 0; ks < 8; ++ks) {
        const short8 bfr = *(const short8*)(gp + ks * 32);
        #pragma unroll
        for (int dt = 0; dt < 4; ++dt) {
            const short8 afr = *(const short8*)(vp + (size_t)dt * 16 * NN + ks * 32);
            acc[dt] = __builtin_amdgcn_mfma_f32_16x16x32_bf16(afr, bfr, acc[dt], 0, 0, 0);
        }
    }

    unsigned short* op = Vgt + (size_t)bh * DD * NN;
    #pragma unroll
    for (int dt = 0; dt < 4; ++dt)
        #pragma unroll
        for (int r = 0; r < 4; ++r)
            op[(size_t)(dt * 16 + lg * 4 + r) * NN + n0 + lr] = f2bf(acc[dt][r]);
}

// ---------------------------------------------------------------------------
// Kernel 5: softmax(scores) @ Vg + projection. 512 threads, wave = head.
// grid 256 (b x 16 n-tiles), LDS 33.3 KB.
// ---------------------------------------------------------------------------
__global__ __launch_bounds__(512) void out_kernel(
    const float* __restrict__ scores, const unsigned short* __restrict__ Vgt,
    const float* __restrict__ Wo, const float* __restrict__ bo,
    float* __restrict__ att_out)
{
    __shared__ float o_l[16][521];
    const int b  = blockIdx.x >> 4;
    const int nt = blockIdx.x & 15;
    const int n0 = nt * 16;
    const int tid = threadIdx.x;
    const int w = tid >> 6, l = tid & 63;
    const int lr = l & 15, lg = l >> 4;
    const int h = w;                          // one head per wave

    {
        const float* sp = scores + ((size_t)(b * HH + h) * NN + n0 + lr) * NN + lg * 8;
        float s[64];
        #pragma unroll
        for (int ks = 0; ks < 8; ++ks) {
            const float4 x0 = *(const float4*)(sp + ks * 32);
            const float4 x1 = *(const float4*)(sp + ks * 32 + 4);
            s[ks * 8 + 0] = x0.x; s[ks * 8 + 1] = x0.y;
            s[ks * 8 + 2] = x0.z; s[ks * 8 + 3] = x0.w;
            s[ks * 8 + 4] = x1.x; s[ks * 8 + 5] = x1.y;
            s[ks * 8 + 6] = x1.z; s[ks * 8 + 7] = x1.w;
        }
        float mx = -1e30f;
        #pragma unroll
        for (int i = 0; i < 64; ++i) mx = fmaxf(mx, s[i]);
        mx = fmaxf(mx, __shfl_xor(mx, 16, 64));
        mx = fmaxf(mx, __shfl_xor(mx, 32, 64));
        float sm = 0.f;
        #pragma unroll
        for (int i = 0; i < 64; ++i) { s[i] = __expf(s[i] - mx); sm += s[i]; }
        sm += __shfl_xor(sm, 16, 64);
        sm += __shfl_xor(sm, 32, 64);
        const float inv = 1.f / sm;

        const unsigned short* vp = Vgt + ((size_t)(b * HH + h) * DD + lr) * NN + lg * 8;
        f32x4 acc[4];
        #pragma unroll
        for (int dt = 0; dt < 4; ++dt) acc[dt] = (f32x4){0.f, 0.f, 0.f, 0.f};

        #pragma unroll
        for (int ks = 0; ks < 8; ++ks) {
            union { short8 v; unsigned short u[8]; } bf;
            #pragma unroll
            for (int j = 0; j < 8; ++j) bf.u[j] = f2bf(s[ks * 8 + j] * inv);
            #pragma unroll
            for (int dt = 0; dt < 4; ++dt) {
                const short8 afr = *(const short8*)(vp + (size_t)dt * 16 * NN + ks * 32);
                acc[dt] = __builtin_amdgcn_mfma_f32_16x16x32_bf16(afr, bf.v, acc[dt], 0, 0, 0);
            }
        }
        // C: row = d' = dt*16+lg*4+r, col = n' = lr
        #pragma unroll
        for (int dt = 0; dt < 4; ++dt)
            #pragma unroll
            for (int r = 0; r < 4; ++r)
                o_l[lr][h * 64 + dt * 16 + lg * 4 + r] = acc[dt][r];
    }
    __syncthreads();

    // projection: thread (n = tid>>5, d-pair = (tid&31)*2); Wo coalesced
    const int n  = tid >> 5;
    const int d2 = (tid & 31) << 1;
    float a0 = bo[d2], a1 = bo[d2 + 1];
    const float* orow = &o_l[n][0];
    #pragma unroll 8
    for (int k = 0; k < 512; ++k) {
        const float o = orow[k];
        const float2 w2 = *(const float2*)(Wo + (size_t)k * 64 + d2);
        a0 += o * w2.x; a1 += o * w2.y;
    }
    *(float2*)(att_out + ((size_t)(b * NN + n0 + n)) * DD + d2) = make_float2(a0, a1);
}

extern "C" void kernel_launch(void* const* d_in, const int* in_sizes, int n_in,
                              void* d_out, int out_size, void* d_ws, size_t ws_size,
                              hipStream_t stream)
{
    const float* query = (const float*)d_in[0];
    const float* edges = (const float*)d_in[1];
    const float* Wq = (const float*)d_in[2];  const float* bq = (const float*)d_in[3];
    const float* Wk = (const float*)d_in[4];  const float* bk = (const float*)d_in[5];
    const float* Wv = (const float*)d_in[6];  const float* bv = (const float*)d_in[7];
    const float* Wa = (const float*)d_in[8];  const float* ba = (const float*)d_in[9];
    const float* Wg = (const float*)d_in[10]; const float* bg = (const float*)d_in[11];
    const float* Wo = (const float*)d_in[12]; const float* bo = (const float*)d_in[13];
    const float* We = (const float*)d_in[14]; const float* be = (const float*)d_in[15];

    float* att_out   = (float*)d_out;
    float* edges_out = (float*)d_out + 262144;  // B*N*D

    char* base = (char*)d_ws;
    float*          scores = (float*)base;                          // 33,554,432 B
    unsigned short* gates  = (unsigned short*)(base + 33554432);    // 16,777,216 B
    unsigned short* Qb     = (unsigned short*)(base + 50331648);    //  4,194,304 B
    unsigned short* Kb     = (unsigned short*)(base + 54525952);    //  4,194,304 B
    unsigned short* Vtb    = (unsigned short*)(base + 58720256);    //  4,194,304 B
    unsigned short* Vgt    = (unsigned short*)(base + 62914560);    //  4,194,304 B

    hipLaunchKernelGGL(qkv_kernel, dim3(1536), dim3(256), 0, stream,
                       query, Wq, bq, Wk, bk, Wv, bv, Qb, Kb, Vtb);
    hipLaunchKernelGGL(qk_kernel, dim3(1024), dim3(256), 0, stream,
                       Qb, Kb, scores);
    hipLaunchKernelGGL(edges_kernel, dim3(8192), dim3(256), 0, stream,
                       edges, Wa, ba, Wg, bg, We, be, scores, gates, edges_out);
    hipLaunchKernelGGL(vg_kernel, dim3(512), dim3(256), 0, stream,
                       gates, Vtb, Vgt);
    hipLaunchKernelGGL(out_kernel, dim3(256), dim3(512), 0, stream,
                       scores, Vgt, Wo, bo, att_out);
}

// Round 4
// 575.784 us; speedup vs baseline: 1.4316x; 1.0227x over previous
//
#include <hip/hip_runtime.h>

#define BB 16
#define NN 256
#define DD 64
#define EE 64
#define HH 8

typedef __attribute__((ext_vector_type(4))) float f32x4;
typedef __attribute__((ext_vector_type(8))) short short8;

__device__ __forceinline__ void fma4(float* acc, float x, float4 w) {
    acc[0] += x * w.x; acc[1] += x * w.y; acc[2] += x * w.z; acc[3] += x * w.w;
}

// fp32 -> bf16 round-to-nearest-even
__device__ __forceinline__ unsigned short f2bf(float f) {
    union { float f; unsigned u; } v; v.f = f;
    unsigned r = v.u + 0x7FFFu + ((v.u >> 16) & 1u);
    return (unsigned short)(r >> 16);
}

// ---------------------------------------------------------------------------
// Kernel 1: QKV projection (fp32 compute), bf16 outputs:
//   Qb [b,h,n,d] (pre-scaled by 0.125), Kb [b,h,n,d], Vtb [b,h,d,n] (transposed).
// grid 1536 (mtx x b x n-tile-of-8), 256 threads.
// ---------------------------------------------------------------------------
__global__ __launch_bounds__(256) void qkv_kernel(
    const float* __restrict__ query,
    const float* __restrict__ Wq, const float* __restrict__ bq,
    const float* __restrict__ Wk, const float* __restrict__ bk,
    const float* __restrict__ Wv, const float* __restrict__ bv,
    unsigned short* __restrict__ Qb, unsigned short* __restrict__ Kb,
    unsigned short* __restrict__ Vtb)
{
    __shared__ __align__(16) float q_l[8][64];
    const int mtx = blockIdx.x >> 9;          // 0:Q 1:K 2:V
    const int rem = blockIdx.x & 511;
    const int b   = rem >> 5;
    const int n0  = (rem & 31) << 3;
    const int tid = threadIdx.x;

    if (tid < 128)
        ((float4*)&q_l[0][0])[tid] =
            ((const float4*)(query + (size_t)(b * NN + n0) * DD))[tid];

    const int w    = tid >> 6;                // wave -> rows 2w, 2w+1
    const int lane = tid & 63;
    const int r0   = w * 2;
    const float* W  = (mtx == 0) ? Wq : (mtx == 1) ? Wk : Wv;
    const float* bs = (mtx == 0) ? bq : (mtx == 1) ? bk : bv;

    const int c0 = lane << 2;
    float acc[2][2][4];
    {
        const float4 b0 = *(const float4*)(bs + c0);
        const float4 b1 = *(const float4*)(bs + 256 + c0);
        acc[0][0][0]=b0.x; acc[0][0][1]=b0.y; acc[0][0][2]=b0.z; acc[0][0][3]=b0.w;
        acc[0][1][0]=b1.x; acc[0][1][1]=b1.y; acc[0][1][2]=b1.z; acc[0][1][3]=b1.w;
        acc[1][0][0]=b0.x; acc[1][0][1]=b0.y; acc[1][0][2]=b0.z; acc[1][0][3]=b0.w;
        acc[1][1][0]=b1.x; acc[1][1][1]=b1.y; acc[1][1][2]=b1.z; acc[1][1][3]=b1.w;
    }
    __syncthreads();

    #pragma unroll 2
    for (int d4 = 0; d4 < 16; ++d4) {
        const float4 qa = ((const float4*)&q_l[r0][0])[d4];
        const float4 qb = ((const float4*)&q_l[r0 + 1][0])[d4];
        const float qav[4] = {qa.x, qa.y, qa.z, qa.w};
        const float qbv[4] = {qb.x, qb.y, qb.z, qb.w};
        #pragma unroll
        for (int k = 0; k < 4; ++k) {
            const float4 w0 = *(const float4*)(W + (size_t)(d4 * 4 + k) * 512 + c0);
            const float4 w1 = *(const float4*)(W + (size_t)(d4 * 4 + k) * 512 + 256 + c0);
            fma4(acc[0][0], qav[k], w0); fma4(acc[0][1], qav[k], w1);
            fma4(acc[1][0], qbv[k], w0); fma4(acc[1][1], qbv[k], w1);
        }
    }

    const int hq = lane >> 4;                 // h within j-half
    const int d0 = (lane & 15) << 2;
    if (mtx < 2) {
        unsigned short* T = (mtx == 0) ? Qb : Kb;
        const float scale = (mtx == 0) ? 0.125f : 1.0f;
        #pragma unroll
        for (int r = 0; r < 2; ++r)
            #pragma unroll
            for (int j = 0; j < 2; ++j) {
                const int h = j * 4 + hq;
                const unsigned int lo = (unsigned)f2bf(acc[r][j][0] * scale)
                                      | ((unsigned)f2bf(acc[r][j][1] * scale) << 16);
                const unsigned int hi = (unsigned)f2bf(acc[r][j][2] * scale)
                                      | ((unsigned)f2bf(acc[r][j][3] * scale) << 16);
                uint2* p = (uint2*)(T + ((size_t)(b * HH + h) * NN + n0 + r0 + r) * DD + d0);
                *p = make_uint2(lo, hi);
            }
    } else {
        #pragma unroll
        for (int r = 0; r < 2; ++r)
            #pragma unroll
            for (int j = 0; j < 2; ++j) {
                const int h = j * 4 + hq;
                #pragma unroll
                for (int k = 0; k < 4; ++k)
                    Vtb[((size_t)(b * HH + h) * DD + d0 + k) * NN + n0 + r0 + r] =
                        f2bf(acc[r][j][k]);
            }
    }
}

// ---------------------------------------------------------------------------
// Kernel 2: scores = (Q @ K^T)/8 via bf16 MFMA (scale folded into Qb).
// grid 1024 (bh x 4 n-tiles-of-64 x 2 m-halves-of-128), 256 thr, no LDS.
// ---------------------------------------------------------------------------
__global__ __launch_bounds__(256) void qk_kernel(
    const unsigned short* __restrict__ Qb, const unsigned short* __restrict__ Kb,
    float* __restrict__ scores)
{
    const int bh = blockIdx.x >> 3;
    const int nt = (blockIdx.x >> 1) & 3;
    const int mh = blockIdx.x & 1;
    const int tid = threadIdx.x;
    const int w = tid >> 6, l = tid & 63;
    const int lr = l & 15, lg = l >> 4;
    const int n0 = nt * 64 + w * 16;

    const unsigned short* qp = Qb + ((size_t)bh * NN + n0 + lr) * DD + lg * 8;
    const unsigned short* kp = Kb + ((size_t)bh * NN + mh * 128 + lr) * DD + lg * 8;

    const short8 a0 = *(const short8*)qp;
    const short8 a1 = *(const short8*)(qp + 32);

    f32x4 acc[8];
    #pragma unroll
    for (int mt = 0; mt < 8; ++mt) acc[mt] = (f32x4){0.f, 0.f, 0.f, 0.f};

    #pragma unroll
    for (int mt = 0; mt < 8; ++mt) {
        const short8 b0 = *(const short8*)(kp + (size_t)mt * 16 * DD);
        const short8 b1 = *(const short8*)(kp + (size_t)mt * 16 * DD + 32);
        acc[mt] = __builtin_amdgcn_mfma_f32_16x16x32_bf16(a0, b0, acc[mt], 0, 0, 0);
        acc[mt] = __builtin_amdgcn_mfma_f32_16x16x32_bf16(a1, b1, acc[mt], 0, 0, 0);
    }

    float* sp = scores + (size_t)bh * NN * NN;
    #pragma unroll
    for (int mt = 0; mt < 8; ++mt)
        #pragma unroll
        for (int r = 0; r < 4; ++r)
            sp[(size_t)(n0 + lg * 4 + r) * NN + mh * 128 + mt * 16 + lr] = acc[mt][r];
}

// ---------------------------------------------------------------------------
// Kernel 3: fused edges pass, fully coalesced + latency-hoisted.
//   qk preload issued at kernel entry (hides under edges staging).
//   edges loads / edges_out stores nontemporal (single-use streams).
// grid 8192, 256 threads, LDS ~28.5 KB -> 5 blocks/CU.
// ---------------------------------------------------------------------------
__global__ __launch_bounds__(256) void edges_kernel(
    const float* __restrict__ edges,
    const float* __restrict__ Wa, const float* __restrict__ ba,
    const float* __restrict__ Wg, const float* __restrict__ bg,
    const float* __restrict__ We, const float* __restrict__ be,
    float* __restrict__ scores,
    unsigned short* __restrict__ gates,
    float* __restrict__ edges_out)
{
    __shared__ __align__(16) unsigned short eb[128 * 64];   // 16 KB, swizzled
    __shared__ __align__(16) unsigned short wc[16 * 64];    //  2 KB, WcatT[h'][e]
    __shared__ __align__(16) float bgl[128][20];            // 10 KB, 16B-aligned rows
    __shared__ float bal[8], bgb[8];

    const int mh  = blockIdx.x & 1;
    const int n   = (blockIdx.x >> 1) & 255;
    const int b   = blockIdx.x >> 9;
    const int m0  = mh << 7;
    const int tid = threadIdx.x;
    const int w   = tid >> 6, l = tid & 63;
    const int lr  = l & 15, lg = l >> 4;

    // ---- hoisted fixup-phase loads: issue FIRST, latency hides under staging
    const int fm = tid & 127;                 // fixup m
    const int fh = (tid >> 7) << 2;           // fixup first-h
    const size_t so0 = ((size_t)(b * HH + fh) << 16) + ((size_t)n << 8) + m0 + fm;
    float qk[4];
    #pragma unroll
    for (int i = 0; i < 4; ++i) qk[i] = scores[so0 + ((size_t)i << 16)];

    // phase-2 constants
    float wecol[8];
    #pragma unroll
    for (int h = 0; h < 8; ++h) wecol[h] = We[h * EE + l];
    const float bev = be[l];

    // --- stage WcatT[h'][e] bf16 (h'<8 -> Wa, else Wg), swizzled
    #pragma unroll
    for (int j = 0; j < 4; ++j) {
        const int idx = tid * 4 + j;
        const int hp = idx >> 6, e = idx & 63;
        const float v = (hp < 8) ? Wa[e * 8 + hp] : Wg[e * 8 + (hp - 8)];
        *(unsigned short*)((char*)wc + hp * 128 + ((e * 2) ^ ((hp & 7) << 4))) = f2bf(v);
    }
    if (tid < 8) { bal[tid] = ba[tid]; bgb[tid] = bg[tid]; }

    // --- stage edges tile [128][64] fp32 -> bf16 LDS, nontemporal coalesced
    const f32x4* esrc = (const f32x4*)(edges + ((size_t)(b * NN + n) * NN + m0) * DD);
    #pragma unroll
    for (int it = 0; it < 8; ++it) {
        const int c = it * 256 + tid;            // float4 index: m = c>>4, e4 = c&15
        const f32x4 x = __builtin_nontemporal_load(esrc + c);
        const int m = c >> 4, e4 = c & 15;
        const unsigned lo = (unsigned)f2bf(x[0]) | ((unsigned)f2bf(x[1]) << 16);
        const unsigned hi = (unsigned)f2bf(x[2]) | ((unsigned)f2bf(x[3]) << 16);
        *(uint2*)((char*)eb + m * 128 + ((e4 * 8) ^ ((m & 7) << 4))) = make_uint2(lo, hi);
    }
    __syncthreads();

    // --- B fragments (WcatT rows, conflict-free via swizzle)
    short8 bfrag[2];
    #pragma unroll
    for (int ks = 0; ks < 2; ++ks)
        bfrag[ks] = *(const short8*)((char*)wc + lr * 128 +
                                     ((ks * 64 + lg * 16) ^ ((lr & 7) << 4)));

    // --- MFMA MLP: wave w owns m-tiles {2w, 2w+1}
    #pragma unroll
    for (int t = 0; t < 2; ++t) {
        const int T = w * 2 + t;
        f32x4 acc = (f32x4){0.f, 0.f, 0.f, 0.f};
        #pragma unroll
        for (int ks = 0; ks < 2; ++ks) {
            const int m = T * 16 + lr;
            const short8 af = *(const short8*)((char*)eb + m * 128 +
                                 ((ks * 64 + lg * 16) ^ ((lr & 7) << 4)));
            acc = __builtin_amdgcn_mfma_f32_16x16x32_bf16(af, bfrag[ks], acc, 0, 0, 0);
        }
        // C: col (h') = lr, row (m-in-tile) = lg*4 + r
        #pragma unroll
        for (int r = 0; r < 4; ++r)
            bgl[T * 16 + lg * 4 + r][lr] = acc[r];
    }
    __syncthreads();

    // --- fixup (qk preloaded): coalesced score/gate writes
    #pragma unroll
    for (int i = 0; i < 4; ++i) {
        const int h = fh + i;
        const float sc = qk[i] + bgl[fm][h] + bal[h];
        scores[so0 + ((size_t)i << 16)] = sc;
        bgl[fm][h] = sc;                      // slot owned by this thread
        const float gv = bgl[fm][8 + h] + bgb[h];
        gates[so0 + ((size_t)i << 16)] = f2bf(1.f / (1.f + __expf(-gv)));
    }
    __syncthreads();

    // --- phase 2: edges_out[b, m, n, e] = sum_h sc[m][h] * We[h][e] + be[e]
    #pragma unroll 4
    for (int mi = 0; mi < 32; ++mi) {
        const int m = w * 32 + mi;
        const float4 sa = *(const float4*)&bgl[m][0];   // wave-broadcast b128
        const float4 sb = *(const float4*)&bgl[m][4];
        const float v = bev
            + sa.x * wecol[0] + sa.y * wecol[1] + sa.z * wecol[2] + sa.w * wecol[3]
            + sb.x * wecol[4] + sb.y * wecol[5] + sb.z * wecol[6] + sb.w * wecol[7];
        __builtin_nontemporal_store(v,
            edges_out + ((size_t)(b * NN + m0 + m) * NN + n) * DD + l);
    }
}

// ---------------------------------------------------------------------------
// Kernel 4: Vgt[b,h,d,n] = (V^T @ g^T) via bf16 MFMA.
// grid 1024 (bh x 4 n-quarters x 2 d-halves), 256 threads, no LDS.
// ---------------------------------------------------------------------------
__global__ __launch_bounds__(256) void vg_kernel(
    const unsigned short* __restrict__ gates, const unsigned short* __restrict__ Vtb,
    unsigned short* __restrict__ Vgt)
{
    const int dh = blockIdx.x & 1;
    const int q  = (blockIdx.x >> 1) & 3;
    const int bh = blockIdx.x >> 3;
    const int tid = threadIdx.x;
    const int w = tid >> 6, l = tid & 63;
    const int lr = l & 15, lg = l >> 4;
    const int n0 = q * 64 + w * 16;

    const unsigned short* gp = gates + ((size_t)bh * NN + n0 + lr) * NN + lg * 8;
    const unsigned short* vp = Vtb + ((size_t)bh * DD + lr) * NN + lg * 8;

    f32x4 acc[2];
    #pragma unroll
    for (int dt = 0; dt < 2; ++dt) acc[dt] = (f32x4){0.f, 0.f, 0.f, 0.f};

    #pragma unroll
    for (int ks = 0; ks < 8; ++ks) {
        const short8 bfr = *(const short8*)(gp + ks * 32);
        #pragma unroll
        for (int dt = 0; dt < 2; ++dt) {
            const short8 afr = *(const short8*)(vp + (size_t)(dh * 2 + dt) * 16 * NN + ks * 32);
            acc[dt] = __builtin_amdgcn_mfma_f32_16x16x32_bf16(afr, bfr, acc[dt], 0, 0, 0);
        }
    }

    unsigned short* op = Vgt + (size_t)bh * DD * NN;
    #pragma unroll
    for (int dt = 0; dt < 2; ++dt)
        #pragma unroll
        for (int r = 0; r < 4; ++r)
            op[(size_t)((dh * 2 + dt) * 16 + lg * 4 + r) * NN + n0 + lr] = f2bf(acc[dt][r]);
}

// ---------------------------------------------------------------------------
// Kernel 5: softmax(scores) @ Vg + projection. 512 threads, wave = head.
// grid 256 (b x 16 n-tiles), LDS 33.3 KB. Nontemporal scores reads
// (last consumer).
// ---------------------------------------------------------------------------
__global__ __launch_bounds__(512) void out_kernel(
    const float* __restrict__ scores, const unsigned short* __restrict__ Vgt,
    const float* __restrict__ Wo, const float* __restrict__ bo,
    float* __restrict__ att_out)
{
    __shared__ float o_l[16][521];
    const int b  = blockIdx.x >> 4;
    const int nt = blockIdx.x & 15;
    const int n0 = nt * 16;
    const int tid = threadIdx.x;
    const int w = tid >> 6, l = tid & 63;
    const int lr = l & 15, lg = l >> 4;
    const int h = w;                          // one head per wave

    {
        const f32x4* sp = (const f32x4*)(scores +
            ((size_t)(b * HH + h) * NN + n0 + lr) * NN + lg * 8);
        float s[64];
        #pragma unroll
        for (int ks = 0; ks < 8; ++ks) {
            const f32x4 x0 = __builtin_nontemporal_load(sp + ks * 8);
            const f32x4 x1 = __builtin_nontemporal_load(sp + ks * 8 + 1);
            s[ks * 8 + 0] = x0[0]; s[ks * 8 + 1] = x0[1];
            s[ks * 8 + 2] = x0[2]; s[ks * 8 + 3] = x0[3];
            s[ks * 8 + 4] = x1[0]; s[ks * 8 + 5] = x1[1];
            s[ks * 8 + 6] = x1[2]; s[ks * 8 + 7] = x1[3];
        }
        float mx = -1e30f;
        #pragma unroll
        for (int i = 0; i < 64; ++i) mx = fmaxf(mx, s[i]);
        mx = fmaxf(mx, __shfl_xor(mx, 16, 64));
        mx = fmaxf(mx, __shfl_xor(mx, 32, 64));
        float sm = 0.f;
        #pragma unroll
        for (int i = 0; i < 64; ++i) { s[i] = __expf(s[i] - mx); sm += s[i]; }
        sm += __shfl_xor(sm, 16, 64);
        sm += __shfl_xor(sm, 32, 64);
        const float inv = 1.f / sm;

        const unsigned short* vp = Vgt + ((size_t)(b * HH + h) * DD + lr) * NN + lg * 8;
        f32x4 acc[4];
        #pragma unroll
        for (int dt = 0; dt < 4; ++dt) acc[dt] = (f32x4){0.f, 0.f, 0.f, 0.f};

        #pragma unroll
        for (int ks = 0; ks < 8; ++ks) {
            union { short8 v; unsigned short u[8]; } bf;
            #pragma unroll
            for (int j = 0; j < 8; ++j) bf.u[j] = f2bf(s[ks * 8 + j] * inv);
            #pragma unroll
            for (int dt = 0; dt < 4; ++dt) {
                const short8 afr = *(const short8*)(vp + (size_t)dt * 16 * NN + ks * 32);
                acc[dt] = __builtin_amdgcn_mfma_f32_16x16x32_bf16(afr, bf.v, acc[dt], 0, 0, 0);
            }
        }
        // C: row = d' = dt*16+lg*4+r, col = n' = lr
        #pragma unroll
        for (int dt = 0; dt < 4; ++dt)
            #pragma unroll
            for (int r = 0; r < 4; ++r)
                o_l[lr][h * 64 + dt * 16 + lg * 4 + r] = acc[dt][r];
    }
    __syncthreads();

    // projection: thread (n = tid>>5, d-pair = (tid&31)*2); Wo coalesced
    const int n  = tid >> 5;
    const int d2 = (tid & 31) << 1;
    float a0 = bo[d2], a1 = bo[d2 + 1];
    const float* orow = &o_l[n][0];
    #pragma unroll 8
    for (int k = 0; k < 512; ++k) {
        const float o = orow[k];
        const float2 w2 = *(const float2*)(Wo + (size_t)k * 64 + d2);
        a0 += o * w2.x; a1 += o * w2.y;
    }
    *(float2*)(att_out + ((size_t)(b * NN + n0 + n)) * DD + d2) = make_float2(a0, a1);
}

extern "C" void kernel_launch(void* const* d_in, const int* in_sizes, int n_in,
                              void* d_out, int out_size, void* d_ws, size_t ws_size,
                              hipStream_t stream)
{
    const float* query = (const float*)d_in[0];
    const float* edges = (const float*)d_in[1];
    const float* Wq = (const float*)d_in[2];  const float* bq = (const float*)d_in[3];
    const float* Wk = (const float*)d_in[4];  const float* bk = (const float*)d_in[5];
    const float* Wv = (const float*)d_in[6];  const float* bv = (const float*)d_in[7];
    const float* Wa = (const float*)d_in[8];  const float* ba = (const float*)d_in[9];
    const float* Wg = (const float*)d_in[10]; const float* bg = (const float*)d_in[11];
    const float* Wo = (const float*)d_in[12]; const float* bo = (const float*)d_in[13];
    const float* We = (const float*)d_in[14]; const float* be = (const float*)d_in[15];

    float* att_out   = (float*)d_out;
    float* edges_out = (float*)d_out + 262144;  // B*N*D

    char* base = (char*)d_ws;
    float*          scores = (float*)base;                          // 33,554,432 B
    unsigned short* gates  = (unsigned short*)(base + 33554432);    // 16,777,216 B
    unsigned short* Qb     = (unsigned short*)(base + 50331648);    //  4,194,304 B
    unsigned short* Kb     = (unsigned short*)(base + 54525952);    //  4,194,304 B
    unsigned short* Vtb    = (unsigned short*)(base + 58720256);    //  4,194,304 B
    unsigned short* Vgt    = (unsigned short*)(base + 62914560);    //  4,194,304 B

    hipLaunchKernelGGL(qkv_kernel, dim3(1536), dim3(256), 0, stream,
                       query, Wq, bq, Wk, bk, Wv, bv, Qb, Kb, Vtb);
    hipLaunchKernelGGL(qk_kernel, dim3(1024), dim3(256), 0, stream,
                       Qb, Kb, scores);
    hipLaunchKernelGGL(edges_kernel, dim3(8192), dim3(256), 0, stream,
                       edges, Wa, ba, Wg, bg, We, be, scores, gates, edges_out);
    hipLaunchKernelGGL(vg_kernel, dim3(1024), dim3(256), 0, stream,
                       gates, Vtb, Vgt);
    hipLaunchKernelGGL(out_kernel, dim3(256), dim3(512), 0, stream,
                       scores, Vgt, Wo, bo, att_out);
}